// Round 7
// baseline (22.817 us; speedup 1.0000x reference)
//
#include <hip/hip_runtime.h>

namespace {
constexpr int Bc  = 16;
constexpr int Nc  = 96;
constexpr int KRc = 16;
constexpr int KAc = 8;
constexpr int NOUT = KRc + KAc;        // 24
constexpr int NNb  = Nc - 1;           // 95 neighbors per atom
constexpr float RCRf = 5.2f;
constexpr float RCAf = 3.5f;
constexpr float L2E  = 1.4426950408889634f;
}

typedef float v2f __attribute__((ext_vector_type(2)));
typedef float v4f __attribute__((ext_vector_type(4)));

__device__ __forceinline__ v2f sp(float x) { return (v2f){x, x}; }
__device__ __forceinline__ v2f pfma(v2f a, v2f b, v2f c) {
    return __builtin_elementwise_fma(a, b, c);
}
__device__ __forceinline__ v2f pmax(v2f a, v2f b) {
    return __builtin_elementwise_max(a, b);
}
__device__ __forceinline__ v2f pexp2(v2f x) {
    return (v2f){__builtin_amdgcn_exp2f(x.x), __builtin_amdgcn_exp2f(x.y)};
}
__device__ __forceinline__ v2f pcosr(v2f rev) {   // cos(2*pi*rev), rev >= 0
    return (v2f){__builtin_amdgcn_cosf(__builtin_amdgcn_fractf(rev.x)),
                 __builtin_amdgcn_cosf(__builtin_amdgcn_fractf(rev.y))};
}
__device__ __forceinline__ v2f psqrt(v2f x) {
    return (v2f){__builtin_amdgcn_sqrtf(x.x), __builtin_amdgcn_sqrtf(x.y)};
}
__device__ __forceinline__ float cos_rev(float rev) {
    return __builtin_amdgcn_cosf(__builtin_amdgcn_fractf(rev));
}

// 320 threads/block, grid 1536 -> 6 blocks/CU = 1920 thr = 30 waves/CU in ONE
// round (needs VGPR<=64, forced by launch_bounds(320,8)).
// Angular: 285 active threads = 3 groups x 95 columns. Thread owns column
// j = t%95 (A operand in registers); group g = t/95 owns packed rounds
// rp = 8g..8g+7 (rr = 2*rp+1; y-lane pair rr+1). Last slot (rp=23) masks the
// rr==48 y-lane. Pairs (j, (j+rr) mod 95), rr=1..47: exact cover of C(95,2).
__global__ __launch_bounds__(320, 8) void ani_feat_kernel(
    const float* __restrict__ coords,      // (B,N,3)
    const int*   __restrict__ atom_types,  // (N,)
    const float* __restrict__ EtaR,        // (T,KR)
    const float* __restrict__ ShfR,        // (T,KR)
    const float* __restrict__ Zeta,        // (T,KA)
    const float* __restrict__ EtaA,        // (T,KA)
    float* __restrict__ out)               // (B,N,24)
{
    const int bi = blockIdx.x;             // b*N + i
    const int b  = bi / Nc;
    const int i  = bi - b * Nc;
    const int t  = threadIdx.x;

    __shared__ float4 su[NNb];             // unit vec x,y,z + d
    __shared__ float  ufa[NNb], sfr[NNb];
    __shared__ v4f  pxy[NNb];              // {x[s],x[s+1],y[s],y[s+1]}
    __shared__ v4f  pzd[NNb];              // {z[s],z[s+1],d[s],d[s+1]}
    __shared__ v2f  pfa[NNb];              // {fa[s],fa[s+1]}
    __shared__ float pr[20][KRc];
    __shared__ float red[5][KAc];

    const int ti = atom_types[i];

    // ---- phase 1: scalar per-neighbor staging ----
    if (t < NNb) {
        const float* cb = coords + (size_t)(b * Nc) * 3;
        int j = t + (t >= i);
        float dx = cb[i*3+0] - cb[j*3+0];
        float dy = cb[i*3+1] - cb[j*3+1];
        float dz = cb[i*3+2] - cb[j*3+2];
        float d2 = dx*dx + dy*dy + dz*dz;
        float d  = __builtin_amdgcn_sqrtf(d2);
        float inv = 1.0f / d;
        su[t]  = make_float4(dx*inv, dy*inv, dz*inv, d);
        ufa[t] = fmaf(cos_rev(d * (0.5f / RCAf)), 0.5f, 0.5f);
        sfr[t] = fmaf(cos_rev(d * (0.5f / RCRf)), 0.5f, 0.5f);
    }

    // ---- fast-path detection from scalar (uniform) loads only ----
    bool fast;
    float ea0, dLs, c10;
    {
        float z0 = Zeta[ti * KAc + 0];
        bool zu = true;
#pragma unroll
        for (int k = 1; k < KAc; ++k) zu = zu && (Zeta[ti * KAc + k] == z0);
        float e0v = EtaA[ti * KAc + 0] * L2E;
        float e1v = EtaA[ti * KAc + 1] * L2E;
        float dv  = e1v - e0v;
        bool ar = true;
#pragma unroll
        for (int k = 2; k < KAc; ++k) {
            float ev = EtaA[ti * KAc + k] * L2E;
            ar = ar && (fabsf(ev - (e0v + dv * (float)k)) <=
                        1e-5f * fabsf(ev) + 1e-7f);
        }
        fast = zu && ar && (z0 == 32.0f);
        ea0 = e0v; dLs = dv; c10 = 1.0f - z0;
    }

    __syncthreads();

    // ---- phase 2: pair-shifted packed SoA for the B operand ----
    if (t < NNb) {
        int s1 = t + 1; if (s1 >= NNb) s1 = 0;
        float4 a = su[t], c = su[s1];
        pxy[t] = (v4f){a.x, c.x, a.y, c.y};
        pzd[t] = (v4f){a.z, c.z, a.w, c.w};
        pfa[t] = (v2f){ufa[t], ufa[s1]};
    }

    // ---- radial G2 (all 320 threads: 20 groups x 16 k) ----
    {
        const int k = t & 15, g2 = t >> 4;      // g2 in 0..19
        float er  = EtaR[ti * KRc + k];
        float sr  = ShfR[ti * KRc + k];
        float erL = -er * L2E;
        float acc = 0.0f;
        for (int jj = g2; jj < NNb; jj += 20) {
            float dd = su[jj].w - sr;
            acc += __builtin_amdgcn_exp2f(erL * dd * dd) * sfr[jj];
        }
        pr[g2][k] = acc;
    }
    __syncthreads();

    // ---- angular G3 ----
    const bool act = (t < 3 * NNb);             // 285 active
    const int  g   = t / NNb;                   // 0..2 (3 for tail, inert)
    const int  j   = t - g * NNb;
    const float4 A  = su[(j < NNb) ? j : 0];
    const float faj = act ? ufa[j] : 0.0f;
    const float d2A  = A.w * A.w;
    const float m2Aw = -2.0f * A.w;
    const int   rr0  = 16 * g + 1;

    float av[KAc];
#pragma unroll
    for (int k = 0; k < KAc; ++k) av[k] = 0.0f;

    if (fast) {
        v2f acc2[KAc];
#pragma unroll
        for (int k = 0; k < KAc; ++k) acc2[k] = sp(0.0f);

        if (act) {
            int j2 = j + rr0; if (j2 >= NNb) j2 -= NNb;
            const v2f fajv  = sp(faj);
            // last packed slot: y-lane is rr==48 for g==2 -> masked
            const v2f lastm = (g == 2) ? (v2f){faj, 0.0f} : fajv;

#define ANG_BODY(FAJV)                                                      \
            {                                                               \
                v4f xy = pxy[j2];                                           \
                v4f zd = pzd[j2];                                           \
                v2f fb = pfa[j2];                                           \
                v2f Bx = xy.xy, By = xy.zw;                                 \
                v2f Bz = zd.xy, Bw = zd.zw;                                 \
                v2f cosv = pfma(sp(A.x), Bx, pfma(sp(A.y), By, sp(A.z)*Bz));\
                v2f sAB  = pfma(Bw, Bw, sp(d2A));                           \
                v2f d23sq = pmax(pfma(sp(m2Aw)*Bw, cosv, sAB), sp(0.0f));   \
                v2f f23 = pfma(pcosr(psqrt(d23sq) * sp(0.5f/RCAf)),         \
                               sp(0.5f), sp(0.5f));                         \
                v2f fprod = (FAJV) * fb * f23;                              \
                v2f s  = sAB + d23sq;                                       \
                v2f tt = pmax(sp(1.0f) + cosv, sp(0.0f));                   \
                v2f t2 = tt*tt, t4 = t2*t2, t8 = t4*t4, t16 = t8*t8;        \
                v2f F  = t16 * t16 * fprod;                                 \
                v2f e0 = pexp2(pfma(sp(-ea0), s, sp(c10)));                 \
                v2f q  = pexp2(sp(-dLs) * s);                               \
                v2f q2 = q * q;                                             \
                v2f e1 = e0*q,  e2 = e0*q2, e3 = e1*q2;                     \
                v2f e4 = e2*q2, e5 = e3*q2, e6 = e4*q2, e7 = e5*q2;         \
                acc2[0] = pfma(F, e0, acc2[0]);                             \
                acc2[1] = pfma(F, e1, acc2[1]);                             \
                acc2[2] = pfma(F, e2, acc2[2]);                             \
                acc2[3] = pfma(F, e3, acc2[3]);                             \
                acc2[4] = pfma(F, e4, acc2[4]);                             \
                acc2[5] = pfma(F, e5, acc2[5]);                             \
                acc2[6] = pfma(F, e6, acc2[6]);                             \
                acc2[7] = pfma(F, e7, acc2[7]);                             \
                j2 += 2; if (j2 >= NNb) j2 -= NNb;                          \
            }

#pragma unroll 2
            for (int it = 0; it < 7; ++it) {
                ANG_BODY(fajv)
            }
            ANG_BODY(lastm)
#undef ANG_BODY
        }
#pragma unroll
        for (int k = 0; k < KAc; ++k) av[k] = acc2[k].x + acc2[k].y;
    } else if (act) {
        // generic fallback: reload params here (keeps fast path lean)
        float zek[KAc], c1k[KAc], eaL[KAc];
#pragma unroll
        for (int k = 0; k < KAc; ++k) {
            float z = Zeta[ti * KAc + k];
            zek[k] = z;
            c1k[k] = 1.0f - z;
            eaL[k] = EtaA[ti * KAc + k] * L2E;
        }
        float accS[KAc];
#pragma unroll
        for (int k = 0; k < KAc; ++k) accS[k] = 0.0f;

        int j2 = j + rr0; if (j2 >= NNb) j2 -= NNb;
        for (int r = 0; r < 16; ++r) {          // 16 scalar pairs
            int rr = rr0 + r;
            float lv = (rr <= 47) ? 1.0f : 0.0f;
            float4 Bq = su[j2];
            float fb = ufa[j2];
            float cosv = fmaf(A.x, Bq.x, fmaf(A.y, Bq.y, A.z * Bq.z));
            float sAB  = fmaf(Bq.w, Bq.w, d2A);
            float d23sq = fmaxf(fmaf(m2Aw * Bq.w, cosv, sAB), 0.0f);
            float d23 = __builtin_amdgcn_sqrtf(d23sq);
            float f23 = fmaf(cos_rev(d23 * (0.5f / RCAf)), 0.5f, 0.5f);
            float fprod = faj * fb * f23 * lv;
            float s  = sAB + d23sq;
            float tt = fmaxf(1.0f + cosv, 0.0f);
            float l2 = __builtin_amdgcn_logf(tt);   // log2; -inf at 0 ok
#pragma unroll
            for (int k = 0; k < KAc; ++k) {
                float E = fmaf(zek[k], l2, c1k[k]);
                E = fmaf(-eaL[k], s, E);
                accS[k] += __builtin_amdgcn_exp2f(E) * fprod;
            }
            ++j2; if (j2 >= NNb) j2 = 0;
        }
#pragma unroll
        for (int k = 0; k < KAc; ++k) av[k] = accS[k];
    }

    // ---- reductions (5 waves) ----
    const int lane = t & 63, wv = t >> 6;
#pragma unroll
    for (int k = 0; k < KAc; ++k) {
        float v = av[k];
#pragma unroll
        for (int off = 32; off; off >>= 1) v += __shfl_xor(v, off, 64);
        if (lane == 0) red[wv][k] = v;
    }
    __syncthreads();

    if (t < KAc) {
        float v = 0.0f;
#pragma unroll
        for (int w = 0; w < 5; ++w) v += red[w][t];
        out[bi * NOUT + KRc + t] = v;
    }
    if (t < KRc) {
        float s = 0.0f;
#pragma unroll
        for (int g2 = 0; g2 < 20; ++g2) s += pr[g2][t];
        out[bi * NOUT + t] = s;
    }
}

extern "C" void kernel_launch(void* const* d_in, const int* in_sizes, int n_in,
                              void* d_out, int out_size, void* d_ws, size_t ws_size,
                              hipStream_t stream) {
    const float* coords     = (const float*)d_in[0];
    const int*   atom_types = (const int*)d_in[1];
    const float* EtaR       = (const float*)d_in[2];
    const float* ShfR       = (const float*)d_in[3];
    const float* Zeta       = (const float*)d_in[4];
    const float* EtaA       = (const float*)d_in[5];
    float* out = (float*)d_out;

    ani_feat_kernel<<<dim3(Bc * Nc), dim3(320), 0, stream>>>(
        coords, atom_types, EtaR, ShfR, Zeta, EtaA, out);
}

// Round 8
// 16.768 us; speedup vs baseline: 1.3608x; 1.3608x over previous
//
#include <hip/hip_runtime.h>

namespace {
constexpr int Bc  = 16;
constexpr int Nc  = 96;
constexpr int KRc = 16;
constexpr int KAc = 8;
constexpr int NOUT = KRc + KAc;        // 24
constexpr int NNb  = Nc - 1;           // 95 neighbors per atom
constexpr int PADN = 144;              // padded pair-shifted arrays (95+49)
constexpr float RCRf = 5.2f;
constexpr float RCAf = 3.5f;
constexpr float L2E  = 1.4426950408889634f;
}

typedef float v2f __attribute__((ext_vector_type(2)));
typedef float v4f __attribute__((ext_vector_type(4)));

__device__ __forceinline__ v2f sp(float x) { return (v2f){x, x}; }
__device__ __forceinline__ v2f pfma(v2f a, v2f b, v2f c) {
    return __builtin_elementwise_fma(a, b, c);
}
__device__ __forceinline__ v2f pmax(v2f a, v2f b) {
    return __builtin_elementwise_max(a, b);
}
__device__ __forceinline__ v2f pexp2(v2f x) {
    return (v2f){__builtin_amdgcn_exp2f(x.x), __builtin_amdgcn_exp2f(x.y)};
}
__device__ __forceinline__ v2f pcosr(v2f rev) {   // cos(2*pi*rev), rev >= 0
    return (v2f){__builtin_amdgcn_cosf(__builtin_amdgcn_fractf(rev.x)),
                 __builtin_amdgcn_cosf(__builtin_amdgcn_fractf(rev.y))};
}
__device__ __forceinline__ v2f psqrt(v2f x) {
    return (v2f){__builtin_amdgcn_sqrtf(x.x), __builtin_amdgcn_sqrtf(x.y)};
}
__device__ __forceinline__ float cos_rev(float rev) {
    return __builtin_amdgcn_cosf(__builtin_amdgcn_fractf(rev));
}

// R5 structure (best measured: 17.5us) + no-wrap padded B arrays:
// 256 thr/block, grid 1536 (6 blocks/CU co-resident), threads t<190 active in
// angular; j = t%95 fixed (A operand in registers), g = t/95 picks rounds
// (g=0: rr 1..24, g=1: rr 25..48 w/ rr==48 y-lane masked). Pair-shifted
// packed B arrays padded to 144 entries (mirror of 0..48) so the 12-iteration
// walk j2 = j+rr0+2*it never wraps -> ds_read with immediate offsets only.
__global__ __launch_bounds__(256, 6) void ani_feat_kernel(
    const float* __restrict__ coords,      // (B,N,3)
    const int*   __restrict__ atom_types,  // (N,)
    const float* __restrict__ EtaR,        // (T,KR)
    const float* __restrict__ ShfR,        // (T,KR)
    const float* __restrict__ Zeta,        // (T,KA)
    const float* __restrict__ EtaA,        // (T,KA)
    float* __restrict__ out)               // (B,N,24)
{
    const int bi = blockIdx.x;             // b*N + i
    const int b  = bi / Nc;
    const int i  = bi - b * Nc;
    const int t  = threadIdx.x;

    __shared__ float4 su[NNb];             // unit vec x,y,z + d
    __shared__ float  ufa[NNb], sfr[NNb];
    __shared__ v4f  pxy[PADN];             // {x[s],x[s1],y[s],y[s1]}
    __shared__ v4f  pzd[PADN];             // {z[s],z[s1],d[s],d[s1]}
    __shared__ v2f  pfa[PADN];             // {fa[s],fa[s1]}
    __shared__ float pr[16][KRc];
    __shared__ float red[4][KAc];

    const int ti = atom_types[i];

    // ---- phase 1: scalar per-neighbor staging ----
    if (t < NNb) {
        const float* cb = coords + (size_t)(b * Nc) * 3;
        int j = t + (t >= i);
        float dx = cb[i*3+0] - cb[j*3+0];
        float dy = cb[i*3+1] - cb[j*3+1];
        float dz = cb[i*3+2] - cb[j*3+2];
        float d2 = dx*dx + dy*dy + dz*dz;
        float d  = __builtin_amdgcn_sqrtf(d2);
        float inv = __builtin_amdgcn_rcpf(d);
        su[t]  = make_float4(dx*inv, dy*inv, dz*inv, d);
        ufa[t] = fmaf(cos_rev(d * (0.5f / RCAf)), 0.5f, 0.5f);
        sfr[t] = fmaf(cos_rev(d * (0.5f / RCRf)), 0.5f, 0.5f);
    }

    // ---- fast-path detection from scalar (uniform) loads only ----
    bool fast;
    float ea0, dLs, c10;
    {
        float z0 = Zeta[ti * KAc + 0];
        bool zu = true;
#pragma unroll
        for (int k = 1; k < KAc; ++k) zu = zu && (Zeta[ti * KAc + k] == z0);
        float e0v = EtaA[ti * KAc + 0] * L2E;
        float e1v = EtaA[ti * KAc + 1] * L2E;
        float dv  = e1v - e0v;
        bool ar = true;
#pragma unroll
        for (int k = 2; k < KAc; ++k) {
            float ev = EtaA[ti * KAc + k] * L2E;
            ar = ar && (fabsf(ev - (e0v + dv * (float)k)) <=
                        1e-5f * fabsf(ev) + 1e-7f);
        }
        fast = zu && ar && (z0 == 32.0f);
        ea0 = e0v; dLs = dv; c10 = 1.0f - z0;
    }

    __syncthreads();

    // ---- phase 2: pair-shifted packed SoA, padded (no wrap in walk) ----
    if (t < NNb) {
        int s1 = t + 1; if (s1 >= NNb) s1 = 0;
        float4 a = su[t], c = su[s1];
        pxy[t] = (v4f){a.x, c.x, a.y, c.y};
        pzd[t] = (v4f){a.z, c.z, a.w, c.w};
        pfa[t] = (v2f){ufa[t], ufa[s1]};
    }
    if (t < PADN - NNb) {                  // mirror slots 0..48 -> 95..143
        int s1 = t + 1;                    // t<=48 -> s1<=49, no wrap
        float4 a = su[t], c = su[s1];
        pxy[NNb + t] = (v4f){a.x, c.x, a.y, c.y};
        pzd[NNb + t] = (v4f){a.z, c.z, a.w, c.w};
        pfa[NNb + t] = (v2f){ufa[t], ufa[s1]};
    }

    // ---- radial G2 (all 256 threads: 16 groups x 16 k) ----
    {
        const int k = t & 15, g2 = t >> 4;
        float er  = EtaR[ti * KRc + k];
        float sr  = ShfR[ti * KRc + k];
        float erL = -er * L2E;
        float acc = 0.0f;
        for (int jj = g2; jj < NNb; jj += 16) {
            float dd = su[jj].w - sr;
            acc += __builtin_amdgcn_exp2f(erL * dd * dd) * sfr[jj];
        }
        pr[g2][k] = acc;
    }
    __syncthreads();

    // ---- angular G3 ----
    const bool act = (t < 2 * NNb);        // 190 active
    const int  g   = (t >= NNb) ? 1 : 0;
    const int  j   = act ? (t - g * NNb) : 0;
    const float4 A  = su[j];
    const float faj = act ? ufa[j] : 0.0f;
    const float d2A  = A.w * A.w;
    const float m2Aw = -2.0f * A.w;
    const int   j2b  = j + (g ? 25 : 1);   // base index into padded arrays

    float av[KAc];

    if (fast) {
        v2f acc2[KAc];
#pragma unroll
        for (int k = 0; k < KAc; ++k) acc2[k] = sp(0.0f);

        if (act) {
            const v2f fajv  = sp(faj);
            const v2f lastm = g ? (v2f){faj, 0.0f} : fajv;  // mask rr==48

#define ANG_IT(IT, FAJV)                                                    \
            {                                                               \
                v4f xy = pxy[j2b + 2 * (IT)];                               \
                v4f zd = pzd[j2b + 2 * (IT)];                               \
                v2f fb = pfa[j2b + 2 * (IT)];                               \
                v2f Bx = xy.xy, By = xy.zw;                                 \
                v2f Bz = zd.xy, Bw = zd.zw;                                 \
                v2f cosv = pfma(sp(A.x), Bx, pfma(sp(A.y), By, sp(A.z)*Bz));\
                v2f sAB  = pfma(Bw, Bw, sp(d2A));                           \
                v2f d23sq = pmax(pfma(sp(m2Aw)*Bw, cosv, sAB), sp(0.0f));   \
                v2f f23 = pfma(pcosr(psqrt(d23sq) * sp(0.5f/RCAf)),         \
                               sp(0.5f), sp(0.5f));                         \
                v2f fprod = (FAJV) * fb * f23;                              \
                v2f s  = sAB + d23sq;                                       \
                v2f tt = pmax(sp(1.0f) + cosv, sp(0.0f));                   \
                v2f t2 = tt*tt, t4 = t2*t2, t8 = t4*t4, t16 = t8*t8;        \
                v2f F  = t16 * t16 * fprod;                                 \
                v2f e0 = pexp2(pfma(sp(-ea0), s, sp(c10)));                 \
                v2f q  = pexp2(sp(-dLs) * s);                               \
                v2f q2 = q * q;                                             \
                v2f e1 = e0*q,  e2 = e0*q2, e3 = e1*q2;                     \
                v2f e4 = e2*q2, e5 = e3*q2, e6 = e4*q2, e7 = e5*q2;         \
                acc2[0] = pfma(F, e0, acc2[0]);                             \
                acc2[1] = pfma(F, e1, acc2[1]);                             \
                acc2[2] = pfma(F, e2, acc2[2]);                             \
                acc2[3] = pfma(F, e3, acc2[3]);                             \
                acc2[4] = pfma(F, e4, acc2[4]);                             \
                acc2[5] = pfma(F, e5, acc2[5]);                             \
                acc2[6] = pfma(F, e6, acc2[6]);                             \
                acc2[7] = pfma(F, e7, acc2[7]);                             \
            }

            ANG_IT(0, fajv)  ANG_IT(1, fajv)  ANG_IT(2, fajv)
            ANG_IT(3, fajv)  ANG_IT(4, fajv)  ANG_IT(5, fajv)
            ANG_IT(6, fajv)  ANG_IT(7, fajv)  ANG_IT(8, fajv)
            ANG_IT(9, fajv)  ANG_IT(10, fajv) ANG_IT(11, lastm)
#undef ANG_IT
        }
#pragma unroll
        for (int k = 0; k < KAc; ++k) av[k] = acc2[k].x + acc2[k].y;
    } else {
        // generic fallback: reload params here (keeps fast path lean)
        float zek[KAc], c1k[KAc], eaL[KAc];
#pragma unroll
        for (int k = 0; k < KAc; ++k) {
            float z = Zeta[ti * KAc + k];
            zek[k] = z;
            c1k[k] = 1.0f - z;
            eaL[k] = EtaA[ti * KAc + k] * L2E;
        }
        float accS[KAc];
#pragma unroll
        for (int k = 0; k < KAc; ++k) accS[k] = 0.0f;

        if (act) {
            for (int r = 0; r < 24; ++r) {
                int rr = (g ? 25 : 1) + r;
                float lv = (rr <= 47) ? 1.0f : 0.0f;
                int j2 = j + rr; if (j2 >= NNb) j2 -= NNb;
                float4 Bq = su[j2];
                float fb = ufa[j2];
                float cosv = fmaf(A.x, Bq.x, fmaf(A.y, Bq.y, A.z * Bq.z));
                float sAB  = fmaf(Bq.w, Bq.w, d2A);
                float d23sq = fmaxf(fmaf(m2Aw * Bq.w, cosv, sAB), 0.0f);
                float d23 = __builtin_amdgcn_sqrtf(d23sq);
                float f23 = fmaf(cos_rev(d23 * (0.5f / RCAf)), 0.5f, 0.5f);
                float fprod = faj * fb * f23 * lv;
                float s  = sAB + d23sq;
                float tt = fmaxf(1.0f + cosv, 0.0f);
                float l2 = __builtin_amdgcn_logf(tt);   // log2; -inf at 0 ok
#pragma unroll
                for (int k = 0; k < KAc; ++k) {
                    float E = fmaf(zek[k], l2, c1k[k]);
                    E = fmaf(-eaL[k], s, E);
                    accS[k] += __builtin_amdgcn_exp2f(E) * fprod;
                }
            }
        }
#pragma unroll
        for (int k = 0; k < KAc; ++k) av[k] = accS[k];
    }

    // ---- reductions ----
    const int lane = t & 63, wv = t >> 6;
#pragma unroll
    for (int k = 0; k < KAc; ++k) {
        float v = av[k];
#pragma unroll
        for (int off = 32; off; off >>= 1) v += __shfl_xor(v, off, 64);
        if (lane == 0) red[wv][k] = v;
    }
    __syncthreads();

    if (t < KAc) {
        out[bi * NOUT + KRc + t] =
            red[0][t] + red[1][t] + red[2][t] + red[3][t];
    }
    if (t < KRc) {
        float s = 0.0f;
#pragma unroll
        for (int g2 = 0; g2 < 16; ++g2) s += pr[g2][t];
        out[bi * NOUT + t] = s;
    }
}

extern "C" void kernel_launch(void* const* d_in, const int* in_sizes, int n_in,
                              void* d_out, int out_size, void* d_ws, size_t ws_size,
                              hipStream_t stream) {
    const float* coords     = (const float*)d_in[0];
    const int*   atom_types = (const int*)d_in[1];
    const float* EtaR       = (const float*)d_in[2];
    const float* ShfR       = (const float*)d_in[3];
    const float* Zeta       = (const float*)d_in[4];
    const float* EtaA       = (const float*)d_in[5];
    float* out = (float*)d_out;

    ani_feat_kernel<<<dim3(Bc * Nc), dim3(256), 0, stream>>>(
        coords, atom_types, EtaR, ShfR, Zeta, EtaA, out);
}